// Round 7
// baseline (343.467 us; speedup 1.0000x reference)
//
#include <hip/hip_runtime.h>

#define TILE 16
#define RR 8
#define ND 17          // 2r+1 displacements per axis
#define HH 512
#define WW 512
#define CC 3
#define BB 4
#define WROWS 32       // window rows/cols in LDS
#define WSTR 36        // window LDS row stride (bank quad = 4*row: phase-conflict-free)
#define SSTR 20        // src LDS row stride (20i%32 distinct over 8-lane phase)
#define BLK 576        // 9 waves per block = one tile

typedef float f4a __attribute__((ext_vector_type(4), aligned(4)));
typedef unsigned long long u64;

static __device__ __forceinline__ int imax(int a, int b) { return a > b ? a : b; }
static __device__ __forceinline__ int imin(int a, int b) { return a < b ? a : b; }

// x + dpp_perm(x) — VALU pipe only.
template <int CTRL>
__device__ __forceinline__ float dpp_add(float x) {
    return x + __int_as_float(
        __builtin_amdgcn_update_dpp(0, __float_as_int(x), CTRL, 0xF, 0xF, true));
}
// x + lane(x ^ 16) via ds_swizzle (LDS pipe)
__device__ __forceinline__ float swz16_add(float x) {
    int y = __builtin_amdgcn_ds_swizzle(__float_as_int(x), (16 << 10) | 0x1F);
    return x + __int_as_float(y);
}

// one dy-pass: chunk-streamed SAD, DPP reduce, per-lane argmin -> packed key
__device__ __forceinline__ u64 sad_pass(const float* Wl, const float S[CC][8],
                                        int dy, int i, int h, int jg) {
    float acc[9];
    #pragma unroll
    for (int a = 0; a < 9; ++a) acc[a] = 0.f;

    #pragma unroll
    for (int c = 0; c < CC; ++c) {
        const int wb = c * (WROWS * WSTR) + (dy + i) * WSTR + 8 * (h + jg);
        // stream 4 f4a chunks; each element col feeds accs a in [col-7, col]
        #pragma unroll
        for (int m = 0; m < 4; ++m) {
            f4a w = *(const f4a*)&Wl[wb + 4 * m];
            #pragma unroll
            for (int e = 0; e < 4; ++e) {
                const int col = 4 * m + e;          // compile-time
                const float we = (e == 0) ? w.x : (e == 1) ? w.y : (e == 2) ? w.z : w.w;
                #pragma unroll
                for (int a = imax(0, col - 7); a <= imin(8, col); ++a)
                    acc[a] += fabsf(we - S[c][col - a]);
            }
        }
    }
    // reduce over lane bits 0..4 (i, jg); bit5 (h) preserved.
    // order matters: xor1, xor2 first so mirror ctrls act as xor4/xor8.
    #pragma unroll
    for (int a = 0; a < 9; ++a) {
        float x = acc[a];
        x = dpp_add<0xB1>(x);     // quad_perm [1,0,3,2] = xor1
        x = dpp_add<0x4E>(x);     // quad_perm [2,3,0,1] = xor2
        x = dpp_add<0x141>(x);    // row_half_mirror (== xor4 after 1,2)
        x = dpp_add<0x140>(x);    // row_mirror      (== xor8 after 1,2,4)
        x = swz16_add(x);         // xor16 (jg)
        acc[a] = x;
    }
    // per-lane argmin, ascending a + strict < keeps smallest dx.
    // dx=8 is computed bit-identically by both h-groups (same partials, same
    // tree) -> duplicate keys are harmless under min.
    float bc = acc[0];
    int   ba = 0;
    #pragma unroll
    for (int a = 1; a < 9; ++a)
        if (acc[a] < bc) { bc = acc[a]; ba = a; }
    const unsigned d = (unsigned)(dy * ND + 8 * h + ba);
    u64 key = ((u64)__float_as_uint(bc) << 32) | d;   // cost>=0: bit order = numeric
    u64 ok  = __shfl_xor(key, 32);                    // other h half
    return ok < key ? ok : key;
}

__global__ __launch_bounds__(BLK, 7) void tile_kernel(const float* __restrict__ src,
                                                      const float* __restrict__ dst,
                                                      const int* __restrict__ offset,
                                                      float* __restrict__ out) {
    __shared__ float Wl[CC * WROWS * WSTR];   // 13824 B
    __shared__ float Sl[CC * TILE * SSTR];    //  3840 B
    __shared__ u64   keyL[9];

    const int bid  = blockIdx.x;
    const int tile = ((bid & 7) << 9) | (bid >> 3);  // XCD-banding swizzle
    const int b  = tile >> 10;
    const int th = (tile >> 5) & 31;
    const int tw = tile & 31;
    const int ti = th * TILE, tj = tw * TILE;
    const int oy = offset[(b * 2 + 0) * 1024 + th * 32 + tw];
    const int ox = offset[(b * 2 + 1) * 1024 + th * 32 + tw];
    const int t  = threadIdx.x;

    // ---- stage 3x32x32 dst window (zero-padded) coalesced into LDS ----
    const int gy0 = ti + oy - RR;
    const int gx0 = tj + ox - RR;
    for (int k = t; k < CC * WROWS * 8; k += BLK) {   // 768 float4 chunks
        int c   = k >> 8;
        int rem = k & 255;
        int row = rem >> 3;
        int cc  = (rem & 7) << 2;
        int gy = gy0 + row;
        int gx = gx0 + cc;
        float4 v = make_float4(0.f, 0.f, 0.f, 0.f);
        if ((unsigned)gy < HH) {
            const float* p = dst + ((size_t)(b * CC + c) * HH + gy) * WW;
            if ((unsigned)gx <= WW - 4) {
                f4a u = *(const f4a*)(p + gx);
                v = make_float4(u.x, u.y, u.z, u.w);
            } else {
                float* ve = (float*)&v;
                #pragma unroll
                for (int e = 0; e < 4; ++e) {
                    int g = gx + e;
                    if ((unsigned)g < WW) ve[e] = p[g];
                }
            }
        }
        *(f4a*)&Wl[c * (WROWS * WSTR) + row * WSTR + cc] = *(f4a*)&v;
    }
    // ---- stage 3x16x16 src tile (always in-bounds, aligned) ----
    if (t >= 192 && t < 384) {
        int k   = t - 192;                 // 192 float4 chunks
        int c   = k >> 6;
        int rem = k & 63;
        int row = rem >> 2;
        int cc  = (rem & 3) << 2;
        f4a v = *(const f4a*)(src + ((size_t)(b * CC + c) * HH + ti + row) * WW + tj + cc);
        *(f4a*)&Sl[c * (TILE * SSTR) + row * SSTR + cc] = v;
    }
    __syncthreads();

    // lane map: i = bits0..3 (row), jg = bit4 (j half), h = bit5 (dx group)
    const int wv = t >> 6;
    const int l  = t & 63;
    const int i  = l & 15;
    const int jg = (l >> 4) & 1;
    const int h  = l >> 5;

    float S[CC][8];
    #pragma unroll
    for (int c = 0; c < CC; ++c) {
        const int sb = c * (TILE * SSTR) + i * SSTR + 8 * jg;
        f4a s0 = *(const f4a*)&Sl[sb];
        f4a s1 = *(const f4a*)&Sl[sb + 4];
        S[c][0]=s0.x; S[c][1]=s0.y; S[c][2]=s0.z; S[c][3]=s0.w;
        S[c][4]=s1.x; S[c][5]=s1.y; S[c][6]=s1.z; S[c][7]=s1.w;
    }

    u64 bestkey = sad_pass(Wl, S, wv, i, h, jg);          // dy = 0..8
    const int dy2 = 9 + wv;                               // dy = 9..16 (wave 8 skips)
    if (dy2 < ND) {
        u64 k2 = sad_pass(Wl, S, dy2, i, h, jg);
        if (k2 < bestkey) bestkey = k2;
    }
    if (l == 0) keyL[wv] = bestkey;
    __syncthreads();

    // block-wide winner (u64 min; d in low bits gives exact smallest-d ties)
    u64 wk = keyL[0];
    #pragma unroll
    for (int w = 1; w < 9; ++w) { u64 kw = keyL[w]; if (kw < wk) wk = kw; }
    const int d   = (int)(wk & 0xFFFFFFFFu);
    const int bdy = d / ND;
    const int bdx = d - bdy * ND;

    if (t == 0) out[(b * 2 + 0) * 1024 + th * 32 + tw] = (float)(oy + bdy - RR);
    if (t == 1) out[(b * 2 + 1) * 1024 + th * 32 + tw] = (float)(ox + bdx - RR);

    // aligned tile straight from the LDS window (2-way bank alias = free)
    float* aligned = out + BB * 2 * 1024;
    for (int e = t; e < CC * TILE * TILE; e += BLK) {
        int c  = e >> 8;
        int ii = (e >> 4) & 15;
        int jj = e & 15;
        aligned[((size_t)(b * CC + c) * HH + ti + ii) * WW + tj + jj] =
            Wl[c * (WROWS * WSTR) + (bdy + ii) * WSTR + bdx + jj];
    }
}

extern "C" void kernel_launch(void* const* d_in, const int* in_sizes, int n_in,
                              void* d_out, int out_size, void* d_ws, size_t ws_size,
                              hipStream_t stream) {
    const float* src    = (const float*)d_in[0];
    const float* dst    = (const float*)d_in[1];
    const int*   offset = (const int*)d_in[2];
    float*       out    = (float*)d_out;
    tile_kernel<<<dim3(BB * 1024), BLK, 0, stream>>>(src, dst, offset, out);
}

// Round 8
// 157.317 us; speedup vs baseline: 2.1833x; 2.1833x over previous
//
#include <hip/hip_runtime.h>

#define TILE 16
#define RR 8
#define ND 17          // 2r+1 displacements per axis
#define HH 512
#define WW 512
#define CC 3
#define BB 4
#define WROWS 32       // window rows/cols in LDS
#define WSTR 36        // window LDS row stride
#define SSTR 20        // src LDS row stride
#define BLK 576        // 9 waves per block = one tile

typedef float f4a __attribute__((ext_vector_type(4), aligned(4)));
typedef unsigned long long u64;

// force a value to materialize in a VGPR (defeats LDS re-read rematerialization)
#define PINV(x) asm volatile("" : "+v"(x))

// x + dpp_perm(x) — VALU pipe only.
template <int CTRL>
__device__ __forceinline__ float dpp_add(float x) {
    return x + __int_as_float(
        __builtin_amdgcn_update_dpp(0, __float_as_int(x), CTRL, 0xF, 0xF, true));
}
// x + lane(x ^ 16) via ds_swizzle (LDS pipe)
__device__ __forceinline__ float swz16_add(float x) {
    int y = __builtin_amdgcn_ds_swizzle(__float_as_int(x), (16 << 10) | 0x1F);
    return x + __int_as_float(y);
}

// one dy-pass: SAD over LDS window rows, reduce over lane bits 0..4,
// per-lane argmin -> packed (cost<<32 | d) key, min'd across h via shfl.
__device__ __forceinline__ u64 sad_pass(const float* Wl, const float S[CC][8],
                                        int dy, int i, int h, int jg) {
    float acc[9];
    #pragma unroll
    for (int a = 0; a < 9; ++a) acc[a] = 0.f;

    #pragma unroll
    for (int c = 0; c < CC; ++c) {
        const int wb = c * (WROWS * WSTR) + (dy + i) * WSTR + 8 * (h + jg);
        f4a a0 = *(const f4a*)&Wl[wb + 0];
        f4a a1 = *(const f4a*)&Wl[wb + 4];
        f4a a2 = *(const f4a*)&Wl[wb + 8];
        f4a a3 = *(const f4a*)&Wl[wb + 12];
        float W16[16] = { a0.x, a0.y, a0.z, a0.w, a1.x, a1.y, a1.z, a1.w,
                          a2.x, a2.y, a2.z, a2.w, a3.x, a3.y, a3.z, a3.w };
        #pragma unroll
        for (int e = 0; e < 16; ++e) PINV(W16[e]);   // keep resident, no re-reads
        #pragma unroll
        for (int a = 0; a < 9; ++a) {
            float s0 = acc[a];
            #pragma unroll
            for (int jl = 0; jl < 8; ++jl)
                s0 += fabsf(W16[a + jl] - S[c][jl]);
            acc[a] = s0;
        }
    }
    // reduce over lane bits 0..4 (i, jg); bit5 (h) preserved.
    // xor1, xor2 first so the mirror ctrls act as xor4 / xor8.
    #pragma unroll
    for (int a = 0; a < 9; ++a) {
        float x = acc[a];
        x = dpp_add<0xB1>(x);     // quad_perm [1,0,3,2] = xor1
        x = dpp_add<0x4E>(x);     // quad_perm [2,3,0,1] = xor2
        x = dpp_add<0x141>(x);    // row_half_mirror (== xor4 after 1,2)
        x = dpp_add<0x140>(x);    // row_mirror      (== xor8 after 1,2,4)
        x = swz16_add(x);         // xor16 (jg)
        acc[a] = x;
    }
    // per-lane argmin, ascending a + strict < keeps smallest dx.
    // dx=8 is computed bit-identically by both h-groups -> dup key harmless.
    float bc = acc[0];
    int   ba = 0;
    #pragma unroll
    for (int a = 1; a < 9; ++a)
        if (acc[a] < bc) { bc = acc[a]; ba = a; }
    const unsigned d = (unsigned)(dy * ND + 8 * h + ba);
    u64 key = ((u64)__float_as_uint(bc) << 32) | d;   // cost>=0: bit order = numeric
    u64 ok  = __shfl_xor(key, 32);                    // other h half
    return ok < key ? ok : key;
}

__global__ __launch_bounds__(BLK, 6) void tile_kernel(const float* __restrict__ src,
                                                      const float* __restrict__ dst,
                                                      const int* __restrict__ offset,
                                                      float* __restrict__ out) {
    __shared__ float Wl[CC * WROWS * WSTR];   // 13824 B
    __shared__ float Sl[CC * TILE * SSTR];    //  3840 B
    __shared__ u64   keyL[9];

    const int bid  = blockIdx.x;
    const int tile = ((bid & 7) << 9) | (bid >> 3);  // XCD-banding swizzle
    const int b  = tile >> 10;
    const int th = (tile >> 5) & 31;
    const int tw = tile & 31;
    const int ti = th * TILE, tj = tw * TILE;
    const int oy = offset[(b * 2 + 0) * 1024 + th * 32 + tw];
    const int ox = offset[(b * 2 + 1) * 1024 + th * 32 + tw];
    const int t  = threadIdx.x;

    // ---- stage 3x32x32 dst window (zero-padded) coalesced into LDS ----
    const int gy0 = ti + oy - RR;
    const int gx0 = tj + ox - RR;
    for (int k = t; k < CC * WROWS * 8; k += BLK) {   // 768 float4 chunks
        int c   = k >> 8;
        int rem = k & 255;
        int row = rem >> 3;
        int cc  = (rem & 7) << 2;
        int gy = gy0 + row;
        int gx = gx0 + cc;
        float4 v = make_float4(0.f, 0.f, 0.f, 0.f);
        if ((unsigned)gy < HH) {
            const float* p = dst + ((size_t)(b * CC + c) * HH + gy) * WW;
            if ((unsigned)gx <= WW - 4) {
                f4a u = *(const f4a*)(p + gx);
                v = make_float4(u.x, u.y, u.z, u.w);
            } else {
                float* ve = (float*)&v;
                #pragma unroll
                for (int e = 0; e < 4; ++e) {
                    int g = gx + e;
                    if ((unsigned)g < WW) ve[e] = p[g];
                }
            }
        }
        *(f4a*)&Wl[c * (WROWS * WSTR) + row * WSTR + cc] = *(f4a*)&v;
    }
    // ---- stage 3x16x16 src tile (always in-bounds, aligned) ----
    if (t >= 192 && t < 384) {
        int k   = t - 192;                 // 192 float4 chunks
        int c   = k >> 6;
        int rem = k & 63;
        int row = rem >> 2;
        int cc  = (rem & 3) << 2;
        f4a v = *(const f4a*)(src + ((size_t)(b * CC + c) * HH + ti + row) * WW + tj + cc);
        *(f4a*)&Sl[c * (TILE * SSTR) + row * SSTR + cc] = v;
    }
    __syncthreads();

    // lane map: i = bits0..3 (row), jg = bit4 (j half), h = bit5 (dx group)
    const int wv = t >> 6;
    const int l  = t & 63;
    const int i  = l & 15;
    const int jg = (l >> 4) & 1;
    const int h  = l >> 5;

    float S[CC][8];
    #pragma unroll
    for (int c = 0; c < CC; ++c) {
        const int sb = c * (TILE * SSTR) + i * SSTR + 8 * jg;
        f4a s0 = *(const f4a*)&Sl[sb];
        f4a s1 = *(const f4a*)&Sl[sb + 4];
        S[c][0]=s0.x; S[c][1]=s0.y; S[c][2]=s0.z; S[c][3]=s0.w;
        S[c][4]=s1.x; S[c][5]=s1.y; S[c][6]=s1.z; S[c][7]=s1.w;
    }
    #pragma unroll
    for (int c = 0; c < CC; ++c)
        #pragma unroll
        for (int j = 0; j < 8; ++j) PINV(S[c][j]);   // resident across both passes

    u64 bestkey = sad_pass(Wl, S, wv, i, h, jg);          // dy = 0..8
    const int dy2 = 9 + wv;                               // dy = 9..16 (wave 8 skips)
    if (dy2 < ND) {
        u64 k2 = sad_pass(Wl, S, dy2, i, h, jg);
        if (k2 < bestkey) bestkey = k2;
    }
    if (l == 0) keyL[wv] = bestkey;
    __syncthreads();

    // block-wide winner (u64 min; d in low bits gives exact smallest-d ties)
    u64 wk = keyL[0];
    #pragma unroll
    for (int w = 1; w < 9; ++w) { u64 kw = keyL[w]; if (kw < wk) wk = kw; }
    const int d   = (int)(wk & 0xFFFFFFFFu);
    const int bdy = d / ND;
    const int bdx = d - bdy * ND;

    if (t == 0) out[(b * 2 + 0) * 1024 + th * 32 + tw] = (float)(oy + bdy - RR);
    if (t == 1) out[(b * 2 + 1) * 1024 + th * 32 + tw] = (float)(ox + bdx - RR);

    // aligned tile straight from the LDS window
    float* aligned = out + BB * 2 * 1024;
    for (int e = t; e < CC * TILE * TILE; e += BLK) {
        int c  = e >> 8;
        int ii = (e >> 4) & 15;
        int jj = e & 15;
        aligned[((size_t)(b * CC + c) * HH + ti + ii) * WW + tj + jj] =
            Wl[c * (WROWS * WSTR) + (bdy + ii) * WSTR + bdx + jj];
    }
}

extern "C" void kernel_launch(void* const* d_in, const int* in_sizes, int n_in,
                              void* d_out, int out_size, void* d_ws, size_t ws_size,
                              hipStream_t stream) {
    const float* src    = (const float*)d_in[0];
    const float* dst    = (const float*)d_in[1];
    const int*   offset = (const int*)d_in[2];
    float*       out    = (float*)d_out;
    tile_kernel<<<dim3(BB * 1024), BLK, 0, stream>>>(src, dst, offset, out);
}

// Round 9
// 153.016 us; speedup vs baseline: 2.2446x; 1.0281x over previous
//
#include <hip/hip_runtime.h>

#define TILE 16
#define RR 8
#define ND 17          // 2r+1 displacements per axis
#define HH 512
#define WW 512
#define CC 3
#define BB 4
#define WROWS 32       // window rows/cols in LDS
#define WSTR 36        // window LDS row stride (bank = 4i+c mod 32, distinct per i)
#define SSTR 20        // src LDS row stride
#define BLK 576        // 9 waves per block = one tile

typedef float f4a __attribute__((ext_vector_type(4), aligned(4)));
typedef unsigned long long u64;

// x + dpp_perm(x) — VALU pipe only.
template <int CTRL>
__device__ __forceinline__ float dpp_add(float x) {
    return x + __int_as_float(
        __builtin_amdgcn_update_dpp(0, __float_as_int(x), CTRL, 0xF, 0xF, true));
}
// x + lane(x ^ 16) via ds_swizzle (LDS pipe)
__device__ __forceinline__ float swz16_add(float x) {
    int y = __builtin_amdgcn_ds_swizzle(__float_as_int(x), (16 << 10) | 0x1F);
    return x + __int_as_float(y);
}

// one dy-pass: streamed SAD over LDS window row, reduce over lane bits 0..4
// (4 DPP + 1 swizzle), per-lane argmin -> packed (cost<<32 | d) key.
// No PINV, no pinning: compiler streams W chunks (r6-validated, no spill).
__device__ __forceinline__ u64 sad_pass(const float* Wl, const float S[CC][8],
                                        int dy, int i, int h, int jg) {
    float acc[9];
    #pragma unroll
    for (int a = 0; a < 9; ++a) acc[a] = 0.f;

    #pragma unroll
    for (int c = 0; c < CC; ++c) {
        const int wb = c * (WROWS * WSTR) + (dy + i) * WSTR + 8 * (h + jg);
        f4a a0 = *(const f4a*)&Wl[wb + 0];
        f4a a1 = *(const f4a*)&Wl[wb + 4];
        f4a a2 = *(const f4a*)&Wl[wb + 8];
        f4a a3 = *(const f4a*)&Wl[wb + 12];
        float W16[16] = { a0.x, a0.y, a0.z, a0.w, a1.x, a1.y, a1.z, a1.w,
                          a2.x, a2.y, a2.z, a2.w, a3.x, a3.y, a3.z, a3.w };
        #pragma unroll
        for (int a = 0; a < 9; ++a) {
            float s0 = acc[a];
            #pragma unroll
            for (int jl = 0; jl < 8; ++jl)
                s0 += fabsf(W16[a + jl] - S[c][jl]);
            acc[a] = s0;
        }
    }
    // reduce over lane bits 0..4 (i, jg); bit5 (h) preserved.
    // xor1, xor2 first so the mirror ctrls act as xor4 / xor8 (r8-validated).
    #pragma unroll
    for (int a = 0; a < 9; ++a) {
        float x = acc[a];
        x = dpp_add<0xB1>(x);     // quad_perm [1,0,3,2] = xor1
        x = dpp_add<0x4E>(x);     // quad_perm [2,3,0,1] = xor2
        x = dpp_add<0x141>(x);    // row_half_mirror (== xor4 after 1,2)
        x = dpp_add<0x140>(x);    // row_mirror      (== xor8 after 1,2,4)
        x = swz16_add(x);         // xor16 (jg)
        acc[a] = x;
    }
    // per-lane argmin, ascending a + strict < keeps smallest dx.
    // dx=8 is computed bit-identically by both h-groups -> dup key harmless.
    float bc = acc[0];
    int   ba = 0;
    #pragma unroll
    for (int a = 1; a < 9; ++a)
        if (acc[a] < bc) { bc = acc[a]; ba = a; }
    const unsigned d = (unsigned)(dy * ND + 8 * h + ba);
    u64 key = ((u64)__float_as_uint(bc) << 32) | d;   // cost>=0: bit order = numeric
    u64 ok  = __shfl_xor(key, 32);                    // other h half
    return ok < key ? ok : key;
}

__global__ __launch_bounds__(BLK, 6) void tile_kernel(const float* __restrict__ src,
                                                      const float* __restrict__ dst,
                                                      const int* __restrict__ offset,
                                                      float* __restrict__ out) {
    __shared__ float Wl[CC * WROWS * WSTR];   // 13824 B
    __shared__ float Sl[CC * TILE * SSTR];    //  3840 B
    __shared__ u64   keyL[9];

    const int bid  = blockIdx.x;
    const int tile = ((bid & 7) << 9) | (bid >> 3);  // XCD-banding swizzle
    const int b  = tile >> 10;
    const int th = (tile >> 5) & 31;
    const int tw = tile & 31;
    const int ti = th * TILE, tj = tw * TILE;
    const int oy = offset[(b * 2 + 0) * 1024 + th * 32 + tw];
    const int ox = offset[(b * 2 + 1) * 1024 + th * 32 + tw];
    const int t  = threadIdx.x;

    // ---- stage 3x32x32 dst window (zero-padded) coalesced into LDS ----
    const int gy0 = ti + oy - RR;
    const int gx0 = tj + ox - RR;
    for (int k = t; k < CC * WROWS * 8; k += BLK) {   // 768 float4 chunks
        int c   = k >> 8;
        int rem = k & 255;
        int row = rem >> 3;
        int cc  = (rem & 7) << 2;
        int gy = gy0 + row;
        int gx = gx0 + cc;
        float4 v = make_float4(0.f, 0.f, 0.f, 0.f);
        if ((unsigned)gy < HH) {
            const float* p = dst + ((size_t)(b * CC + c) * HH + gy) * WW;
            if ((unsigned)gx <= WW - 4) {
                f4a u = *(const f4a*)(p + gx);
                v = make_float4(u.x, u.y, u.z, u.w);
            } else {
                float* ve = (float*)&v;
                #pragma unroll
                for (int e = 0; e < 4; ++e) {
                    int g = gx + e;
                    if ((unsigned)g < WW) ve[e] = p[g];
                }
            }
        }
        *(f4a*)&Wl[c * (WROWS * WSTR) + row * WSTR + cc] = *(f4a*)&v;
    }
    // ---- stage 3x16x16 src tile (always in-bounds, aligned) ----
    if (t >= 192 && t < 384) {
        int k   = t - 192;                 // 192 float4 chunks
        int c   = k >> 6;
        int rem = k & 63;
        int row = rem >> 2;
        int cc  = (rem & 3) << 2;
        f4a v = *(const f4a*)(src + ((size_t)(b * CC + c) * HH + ti + row) * WW + tj + cc);
        *(f4a*)&Sl[c * (TILE * SSTR) + row * SSTR + cc] = v;
    }
    __syncthreads();

    // lane map: i = bits0..3 (row), jg = bit4 (j half), h = bit5 (dx group)
    const int wv = t >> 6;
    const int l  = t & 63;
    const int i  = l & 15;
    const int jg = (l >> 4) & 1;
    const int h  = l >> 5;

    float S[CC][8];
    #pragma unroll
    for (int c = 0; c < CC; ++c) {
        const int sb = c * (TILE * SSTR) + i * SSTR + 8 * jg;
        f4a s0 = *(const f4a*)&Sl[sb];
        f4a s1 = *(const f4a*)&Sl[sb + 4];
        S[c][0]=s0.x; S[c][1]=s0.y; S[c][2]=s0.z; S[c][3]=s0.w;
        S[c][4]=s1.x; S[c][5]=s1.y; S[c][6]=s1.z; S[c][7]=s1.w;
    }

    u64 bestkey = sad_pass(Wl, S, wv, i, h, jg);          // dy = 0..8
    const int dy2 = 9 + wv;                               // dy = 9..16 (wave 8 skips)
    if (dy2 < ND) {
        u64 k2 = sad_pass(Wl, S, dy2, i, h, jg);
        if (k2 < bestkey) bestkey = k2;
    }
    if (l == 0) keyL[wv] = bestkey;
    __syncthreads();

    // block-wide winner (u64 min; d in low bits gives exact smallest-d ties)
    u64 wk = keyL[0];
    #pragma unroll
    for (int w = 1; w < 9; ++w) { u64 kw = keyL[w]; if (kw < wk) wk = kw; }
    const int d   = (int)(wk & 0xFFFFFFFFu);
    const int bdy = d / ND;
    const int bdx = d - bdy * ND;

    if (t == 0) out[(b * 2 + 0) * 1024 + th * 32 + tw] = (float)(oy + bdy - RR);
    if (t == 1) out[(b * 2 + 1) * 1024 + th * 32 + tw] = (float)(ox + bdx - RR);

    // aligned tile straight from the LDS window
    float* aligned = out + BB * 2 * 1024;
    for (int e = t; e < CC * TILE * TILE; e += BLK) {
        int c  = e >> 8;
        int ii = (e >> 4) & 15;
        int jj = e & 15;
        aligned[((size_t)(b * CC + c) * HH + ti + ii) * WW + tj + jj] =
            Wl[c * (WROWS * WSTR) + (bdy + ii) * WSTR + bdx + jj];
    }
}

extern "C" void kernel_launch(void* const* d_in, const int* in_sizes, int n_in,
                              void* d_out, int out_size, void* d_ws, size_t ws_size,
                              hipStream_t stream) {
    const float* src    = (const float*)d_in[0];
    const float* dst    = (const float*)d_in[1];
    const int*   offset = (const int*)d_in[2];
    float*       out    = (float*)d_out;
    tile_kernel<<<dim3(BB * 1024), BLK, 0, stream>>>(src, dst, offset, out);
}